// Round 6
// baseline (1583.753 us; speedup 1.0000x reference)
//
#include <hip/hip_runtime.h>

// Problem constants
#define B_    64
#define T_    512
#define KDIM  1024
#define HID_  1024

// R18 GEMM geometry: 64x32 tile, 128 threads (2 waves), 4x4/thread, BK=32.
#define BM 64     // t rows per block
#define BN 32     // h cols per block
#define BK 32     // two numpy 16-k blocks per slice
#define LDA 36    // padded LDS row: 32 + 4 floats (9 quad-banks: odd -> reads clean)
#define NSL 32    // slices per block = KDIM/BK
#define ABOFF 2304  // B region offset (64*36 floats)
#define BUFSZ 3456  // per-buffer floats: A 64x36 + B 32x36
// total smem = 2*3456 floats = 27648 B -> 5 blocks/CU by LDS (10 waves)

// f32 correctly rounded from python float math.exp(-1.0/20.0)
#define ALPHA_F 0.95122942450071400909f

typedef float v4f __attribute__((ext_vector_type(4)));
typedef float v2f __attribute__((ext_vector_type(2)));

// Bit-faithful replication of the harness numpy f32 reference: per output
// element 4 f32 accumulator lanes (lane l sums k = l mod 4), 16-k blocks
// ascending (kb 0,1 within slice, slices ascending), q descending within
// block, mul/add separately rounded (no FMA), hadd tree (l0+l1)+(l2+l3), one
// f32 bias add (in the scan kernel, same rounding position), f32 scan.
// Chain identical to R6..R17 (R16/R17 PASSED with this exact split).
//
// R18 vs R17 (GEMM 1430 us, VALUBusy 80.5%, SQ_LDS_BANK_CONFLICT 5.03e7):
// R17's BK=16 staging conflicted structurally: a 16-float row = 4 quad-banks,
// so each 8-lane phase of ds_write_b128 spans 2 rows, and LDA=20 (5-quad row
// stride) makes the two rows' quad sets collide mod 8 -> 2-4-way conflicts
// on every staging write (~80 us of LDS-pipe cycles sitting on the lgkmcnt
// drain before each barrier). R12's BK=32 staging (8 threads x float4 = one
// full 32-float row per phase, LDA=36 = 9 quads, odd) is conflict-free on
// writes AND reads, globally 128B-coalesced per row, and needs zero per-read
// VALU (offsets fold into ds_read immediates). R18 = R17's split + that
// staging: barriers/block halve to 32 (idle amortized over 2048 cy/slice),
// conflicts ~1e6, same 2-wave barrier domains. LDS 27.6 KB -> 5 blocks/CU.
__global__ __launch_bounds__(128, 2) void snn_gemm_np(
    const float* __restrict__ x,     // [B,T,K] f32
    const float* __restrict__ W,     // [H,K] f32
    float* __restrict__ Iout)        // [B,T,H] f32 out (I, no bias)
{
#pragma clang fp contract(off)       // numpy SSE path has no FMA: mul+add only
    __shared__ float smem[2 * BUFSZ];   // 27648 B
    float* const AB0 = smem;            // A @0, B @2304
    float* const AB1 = smem + BUFSZ;

    const int tid = threadIdx.x;
    const int bb  = blockIdx.x;         // batch index
    const int t0  = blockIdx.y * BM;    // t tile origin
    const int h0  = blockIdx.z * BN;    // h tile origin

    const int tx = tid & 7;             // h micro (4 cols, stride 8)
    const int ty = tid >> 3;            // t micro (4 rows, stride 16)

    const int sr = tid >> 3;            // staging row 0..15 (+16m)
    const int sc = (tid & 7) << 2;      // staging col 0,4,..,28

    const float* xb = x + ((size_t)bb * T_ + t0) * KDIM;
    const float* Wb = W + (size_t)h0 * KDIM;

    // ---- prologue: slice 0 -> AB0; slice 1 -> regs ----
    float4 pa0, pa1, pa2, pa3, pw0, pw1;
    pa0 = *(const float4*)&xb[(size_t)(sr)      * KDIM + sc];
    pa1 = *(const float4*)&xb[(size_t)(16 + sr) * KDIM + sc];
    pa2 = *(const float4*)&xb[(size_t)(32 + sr) * KDIM + sc];
    pa3 = *(const float4*)&xb[(size_t)(48 + sr) * KDIM + sc];
    pw0 = *(const float4*)&Wb[(size_t)(sr)      * KDIM + sc];
    pw1 = *(const float4*)&Wb[(size_t)(16 + sr) * KDIM + sc];
    *(float4*)&AB0[(sr)      * LDA + sc]         = pa0;
    *(float4*)&AB0[(16 + sr) * LDA + sc]         = pa1;
    *(float4*)&AB0[(32 + sr) * LDA + sc]         = pa2;
    *(float4*)&AB0[(48 + sr) * LDA + sc]         = pa3;
    *(float4*)&AB0[ABOFF + (sr)      * LDA + sc] = pw0;
    *(float4*)&AB0[ABOFF + (16 + sr) * LDA + sc] = pw1;
    pa0 = *(const float4*)&xb[(size_t)(sr)      * KDIM + 32 + sc];
    pa1 = *(const float4*)&xb[(size_t)(16 + sr) * KDIM + 32 + sc];
    pa2 = *(const float4*)&xb[(size_t)(32 + sr) * KDIM + 32 + sc];
    pa3 = *(const float4*)&xb[(size_t)(48 + sr) * KDIM + 32 + sc];
    pw0 = *(const float4*)&Wb[(size_t)(sr)      * KDIM + 32 + sc];
    pw1 = *(const float4*)&Wb[(size_t)(16 + sr) * KDIM + 32 + sc];
    __syncthreads();                    // AB0 visible

    // numpy 4-lane accumulators, lane-paired: p01 = lanes {0,1}, p23 = {2,3}
    v2f p01[4][4], p23[4][4];
#pragma unroll
    for (int j = 0; j < 4; ++j)
#pragma unroll
        for (int i = 0; i < 4; ++i) {
            p01[j][i] = (v2f)(0.0f);
            p23[j][i] = (v2f)(0.0f);
        }

    for (int s = 0; s < NSL; ++s) {
        float* const cb = (s & 1) ? AB1 : AB0;   // compute buffer (slice s)
        float* const nb = (s & 1) ? AB0 : AB1;   // commit target (slice s+1)

        // 1) commit regs (slice s+1) into nb — overlapped with compute;
        //    nb's old readers finished before the previous barrier.
        if (s + 1 < NSL) {
            *(float4*)&nb[(sr)      * LDA + sc]         = pa0;
            *(float4*)&nb[(16 + sr) * LDA + sc]         = pa1;
            *(float4*)&nb[(32 + sr) * LDA + sc]         = pa2;
            *(float4*)&nb[(48 + sr) * LDA + sc]         = pa3;
            *(float4*)&nb[ABOFF + (sr)      * LDA + sc] = pw0;
            *(float4*)&nb[ABOFF + (16 + sr) * LDA + sc] = pw1;
        }
        // 2) issue slice s+2 loads; a whole compute phase to land.
        if (s + 2 < NSL) {
            const int nk = (s + 2) << 5;
            pa0 = *(const float4*)&xb[(size_t)(sr)      * KDIM + nk + sc];
            pa1 = *(const float4*)&xb[(size_t)(16 + sr) * KDIM + nk + sc];
            pa2 = *(const float4*)&xb[(size_t)(32 + sr) * KDIM + nk + sc];
            pa3 = *(const float4*)&xb[(size_t)(48 + sr) * KDIM + nk + sc];
            pw0 = *(const float4*)&Wb[(size_t)(sr)      * KDIM + nk + sc];
            pw1 = *(const float4*)&Wb[(size_t)(16 + sr) * KDIM + nk + sc];
        }
        // 3) compute slice s: two numpy 16-k blocks ascending; q=3..0 —
        // per-lane acc += a[16kb+4q+l]*b[16kb+4q+l], mul then add: bitwise
        // equal to numpy's chained a0b0+(a1b1+(a2b2+(a3b3+acc)))
#pragma unroll
        for (int kb = 0; kb < 2; ++kb) {
#pragma unroll
            for (int q = 3; q >= 0; --q) {
                const int qc = (kb << 4) + (q << 2);
                v2f a01[4], a23[4], b01[4], b23[4];
#pragma unroll
                for (int j = 0; j < 4; ++j) {
                    const v4f a = *(const v4f*)&cb[(ty + 16 * j) * LDA + qc];
                    a01[j] = a.xy; a23[j] = a.zw;
                }
#pragma unroll
                for (int i = 0; i < 4; ++i) {
                    const v4f b = *(const v4f*)&cb[ABOFF + (tx + 8 * i) * LDA + qc];
                    b01[i] = b.xy; b23[i] = b.zw;
                }
#pragma unroll
                for (int j = 0; j < 4; ++j)
#pragma unroll
                    for (int i = 0; i < 4; ++i) {
                        const v2f m01 = a01[j] * b01[i];   // packed rounded muls
                        const v2f m23 = a23[j] * b23[i];
                        p01[j][i] = p01[j][i] + m01;       // packed rounded adds
                        p23[j][i] = p23[j][i] + m23;
                    }
            }
        }
        __syncthreads();   // slice s reads done; slice s+1 commit visible
    }

    // epilogue: hadd (l0+l1)+(l2+l3); store I (bias added in scan kernel)
    float* const Ob = Iout + ((size_t)bb * T_ + t0) * HID_ + h0;
#pragma unroll
    for (int j = 0; j < 4; ++j)
#pragma unroll
        for (int i = 0; i < 4; ++i) {
            const float s01 = p01[j][i].x + p01[j][i].y;
            const float s23 = p23[j][i].x + p23[j][i].y;
            Ob[(ty + 16 * j) * HID_ + tx + 8 * i] = s01 + s23;
        }
}

// LIF scan, in place over the spikes buffer (each thread owns one (b,h)
// column: strictly read-then-overwrite within the thread, no cross-thread
// sharing). Bias added here: It = s + b (same rounding position as the fused
// version's (s01+s23)+b), then mem = alpha*mem + It — chain unchanged.
// 16-deep register prefetch hides HBM/L3 latency (loads are independent of
// the mem recurrence); arrays fully unrolled -> static indices, no scratch.
__global__ __launch_bounds__(256, 2) void snn_scan(
    float* __restrict__ IS,          // in: I (no bias) / out: spikes, in place
    const float* __restrict__ bias,  // [H]
    float* __restrict__ memf)        // [B,H] f32 out
{
#pragma clang fp contract(off)       // alpha*mem + It must be mul then add
    const int gid = blockIdx.x * 256 + threadIdx.x;
    const int b = gid >> 10;
    const int h = gid & (HID_ - 1);
    float* col = IS + (size_t)b * T_ * HID_ + h;
    const float bv = bias[h];
    float mem = 0.0f;

    float cur[16], nxt[16];
#pragma unroll
    for (int k = 0; k < 16; ++k) cur[k] = col[(size_t)k * HID_];

    for (int tg = 0; tg < T_; tg += 16) {
        if (tg + 16 < T_) {
#pragma unroll
            for (int k = 0; k < 16; ++k)
                nxt[k] = col[(size_t)(tg + 16 + k) * HID_];
        }
#pragma unroll
        for (int k = 0; k < 16; ++k) {
            const float It = cur[k] + bv;     // rounded bias add
            const float am = ALPHA_F * mem;   // rounded mul
            mem = am + It;                    // rounded add
            const bool fire = (mem >= 1.0f);
            col[(size_t)(tg + k) * HID_] = fire ? 1.0f : 0.0f;
            if (fire) mem = 0.0f;
        }
#pragma unroll
        for (int k = 0; k < 16; ++k) cur[k] = nxt[k];
    }
    memf[(size_t)b * HID_ + h] = mem;
}

extern "C" void kernel_launch(void* const* d_in, const int* in_sizes, int n_in,
                              void* d_out, int out_size, void* d_ws, size_t ws_size,
                              hipStream_t stream) {
    const float* x    = (const float*)d_in[0];   // [B,T,K] f32
    const float* W    = (const float*)d_in[1];   // [H,K] f32
    const float* bias = (const float*)d_in[2];   // [H] f32
    float* out    = (float*)d_out;
    float* spikes = out;                          // [B,T,H]
    float* memf   = out + (size_t)B_ * T_ * HID_; // [B,H]

    dim3 g1(B_, T_ / BM, HID_ / BN);   // 64 x 8 x 32 = 16384 blocks
    snn_gemm_np<<<g1, dim3(128), 0, stream>>>(x, W, spikes);

    snn_scan<<<dim3((B_ * HID_) / 256), dim3(256), 0, stream>>>(
        spikes, bias, memf);
}